// Round 3
// baseline (146.642 us; speedup 1.0000x reference)
//
#include <hip/hip_runtime.h>
#include <stdint.h>

// MNISTQuant: out[65536,50] = x[65536,784] @ (int8_w[784,50] * scaler)
// R3: barrier-free streaming. Each wave owns its own 16-row tile (no
// redundant x loads). B pre-dequantized into a fragment-order LDS table
// (4 coltiles x 25 steps x 64 lanes x 16B = 102.4 KB), read-only after
// prologue. Depth-4 per-wave global prefetch; per-wave LDS out staging
// for contiguous stores. Grid = 256 blocks = 1 block/CU (LDS-capped).

typedef __attribute__((ext_vector_type(8))) short bf16x8;
typedef __attribute__((ext_vector_type(4))) float f32x4;

#define IN_F 784
#define OUT_F 50
#define NSTEP 25              // K padded 784 -> 800 (25 x 32)
#define NCT 4                 // col tiles (50 -> 64)
#define NTILES 4096           // 65536 rows / 16
#define NBLK 256              // 1 block/CU
#define NTHREADS 512          // 8 waves
#define TILES_PER_BLK 16      // 2 per wave

__device__ __forceinline__ unsigned short f2bf(float f) {
    unsigned int u = __builtin_bit_cast(unsigned int, f);
    u += 0x7FFFu + ((u >> 16) & 1u);   // round-to-nearest-even
    return (unsigned short)(u >> 16);
}

__global__ __launch_bounds__(NTHREADS, 2) void MNISTQuant_48687749267957_kernel(
    const float* __restrict__ x,
    const int* __restrict__ wq,          // int8 weights delivered as int32
    const float* __restrict__ scaler,
    float* __restrict__ out)
{
    // 102,400 B fragment table + 8 x 3,200 B per-wave out staging = 128,000 B
    __shared__ bf16x8 bfl[NCT * NSTEP * 64];
    __shared__ float  ostage[8][16 * OUT_F];

    const int tid  = threadIdx.x;
    const int lane = tid & 63;
    const int wave = tid >> 6;
    const int arow = lane & 15;          // A row (m) within tile
    const int kgrp = lane >> 4;          // 8-elem k sub-chunk within 32-wide step
    const float scl = scaler[0];

    // ---- Prologue: build fragment-order dequantized B table ----
    // frag g = (ct*25 + s)*64 + l holds B[k = s*32+(l>>4)*8 .. +8][col = ct*16+(l&15)]
    for (int g = tid; g < NCT * NSTEP * 64; g += NTHREADS) {
        const int l   = g & 63;
        const int cs  = g >> 6;
        const int ct  = cs / NSTEP;
        const int s   = cs - ct * NSTEP;
        const int col = ct * 16 + (l & 15);
        const int k0  = s * 32 + (l >> 4) * 8;
        bf16x8 f;
        #pragma unroll
        for (int j = 0; j < 8; ++j) {
            const int k = k0 + j;
            float w = 0.f;
            if (k < IN_F && col < OUT_F)
                w = (float)wq[k * OUT_F + col] * scl;
            f[j] = (short)f2bf(w);
        }
        bfl[g] = f;
    }
    __syncthreads();   // the only barrier; bfl is read-only below

    #pragma unroll 1
    for (int i = 0; i < 2; ++i) {
        const int tile = blockIdx.x * TILES_PER_BLK + wave + i * 8;
        const float* xr = x + (size_t)tile * (16 * IN_F) + (size_t)arow * IN_F + kgrp * 8;

        // depth-4 rotating prefetch
        f32x4 pa[4], pb[4];
        #pragma unroll
        for (int d = 0; d < 4; ++d) {
            pa[d] = *(const f32x4*)(xr + d * 32);
            pb[d] = *(const f32x4*)(xr + d * 32 + 4);
        }

        f32x4 acc[NCT];
        #pragma unroll
        for (int ct = 0; ct < NCT; ++ct) acc[ct] = (f32x4){0.f, 0.f, 0.f, 0.f};

        #pragma unroll
        for (int s = 0; s < NSTEP; ++s) {
            const int d = s & 3;
            bf16x8 a;
            #pragma unroll
            for (int j = 0; j < 4; ++j) {
                a[j]     = (short)f2bf(pa[d][j]);
                a[j + 4] = (short)f2bf(pb[d][j]);
            }
            // K tail: step 24 covers k 768..799, real data ends at 783
            if (s == NSTEP - 1 && kgrp >= 2) {
                #pragma unroll
                for (int j = 0; j < 8; ++j) a[j] = 0;
            }
            // prefetch step s+4 into the freed slot (clamp the OOB tail loads)
            if (s + 4 < NSTEP) {
                int off = (s + 4) * 32;
                if (s + 4 == NSTEP - 1 && kgrp >= 2) off = 0;   // dummy, unused
                pa[d] = *(const f32x4*)(xr + off);
                pb[d] = *(const f32x4*)(xr + off + 4);
            }
            #pragma unroll
            for (int ct = 0; ct < NCT; ++ct)
                acc[ct] = __builtin_amdgcn_mfma_f32_16x16x32_bf16(
                    a, bfl[(ct * NSTEP + s) * 64 + lane], acc[ct], 0, 0, 0);
        }

        // ---- per-wave out staging (no cross-wave sharing -> no barrier) ----
        float* ob = ostage[wave];
        #pragma unroll
        for (int ct = 0; ct < NCT; ++ct) {
            const int col = ct * 16 + arow;       // C col = lane&15 (+ct*16)
            if (col < OUT_F) {
                #pragma unroll
                for (int j = 0; j < 4; ++j)       // C row = (lane>>4)*4 + j
                    ob[(kgrp * 4 + j) * OUT_F + col] = acc[ct][j];
            }
        }
        // same-wave ds_write -> ds_read ordering via lgkmcnt (compiler-inserted)
        float* og = out + (size_t)tile * (16 * OUT_F);
        #pragma unroll
        for (int r = 0; r < 4; ++r) {
            const int idx = lane + r * 64;
            if (idx < (16 * OUT_F) / 4)
                *((f32x4*)og + idx) = *((const f32x4*)ob + idx);
        }
    }
}

extern "C" void kernel_launch(void* const* d_in, const int* in_sizes, int n_in,
                              void* d_out, int out_size, void* d_ws, size_t ws_size,
                              hipStream_t stream) {
    const float* x      = (const float*)d_in[0];
    const int*   wq     = (const int*)d_in[1];
    const float* scaler = (const float*)d_in[2];
    float*       out    = (float*)d_out;
    MNISTQuant_48687749267957_kernel<<<NBLK, NTHREADS, 0, stream>>>(x, wq, scaler, out);
}

// Round 4
// 46.957 us; speedup vs baseline: 3.1229x; 3.1229x over previous
//
#include <hip/hip_runtime.h>
#include <hip/hip_bf16.h>
#include <stdint.h>

// MNISTQuant: out[65536,50] = x[65536,784] @ (int8_w[784,50] * scaler)
// R4: R3 structure (wave-owns-tile, fragment-order dequantized B table in
// LDS, barrier-free steady state) with the rule-#20 scratch spill fixed:
// ALL prefetch/accumulator registers are NAMED (p0a..p3b, acc0..3); runtime
// values only feed address arithmetic. 1024-thr blocks, 16 waves/CU,
// 1 tile/wave, grid=256. Depth-4 global prefetch (8 loads in flight/wave).

typedef __attribute__((ext_vector_type(8))) short bf16x8;
typedef __attribute__((ext_vector_type(4))) float f32x4;

#define IN_F 784
#define OUT_F 50
#define NSTEP 25              // K padded 784 -> 800 (25 x 32)
#define NCT 4                 // col tiles (50 -> 64)
#define NTILES 4096           // 65536 rows / 16
#define NBLK 256              // 1 block/CU
#define NTHREADS 1024         // 16 waves, 1 tile per wave

__device__ __forceinline__ short f2bf(float f) {
    return (short)__builtin_bit_cast(unsigned short, __float2bfloat16(f));
}

__global__ __launch_bounds__(NTHREADS, 4) void MNISTQuant_48687749267957_kernel(
    const float* __restrict__ x,
    const int* __restrict__ wq,          // int8 weights delivered as int32
    const float* __restrict__ scaler,
    float* __restrict__ out)
{
    __shared__ bf16x8 bfl[NCT * NSTEP * 64];      // 102,400 B fragment table
    __shared__ float  ostage[16][16 * OUT_F];     //  51,200 B out staging

    const int tid  = threadIdx.x;
    const int lane = tid & 63;
    const int wave = tid >> 6;
    const int arow = lane & 15;          // A row (m) within tile
    const int kgrp = lane >> 4;          // 8-elem k sub-chunk within 32-wide step
    const float scl = scaler[0];

    // ---- Prologue: fragment-order dequantized B table ----
    // frag g = (ct*25+s)*64 + l holds B[k = s*32+(l>>4)*8 .. +8][col = ct*16+(l&15)]
    for (int g = tid; g < NCT * NSTEP * 64; g += NTHREADS) {
        const int l   = g & 63;
        const int cs  = g >> 6;
        const int ct  = cs / NSTEP;
        const int s   = cs - ct * NSTEP;
        const int col = ct * 16 + (l & 15);
        const int k0  = s * 32 + (l >> 4) * 8;
        bf16x8 f;
        #pragma unroll
        for (int j = 0; j < 8; ++j) {
            const int k = k0 + j;
            float w = 0.f;
            if (k < IN_F && col < OUT_F)
                w = (float)wq[k * OUT_F + col] * scl;
            f[j] = f2bf(w);
        }
        bfl[g] = f;
    }
    __syncthreads();   // only barrier; bfl read-only below

    const int tile = blockIdx.x * 16 + wave;
    const float* xr = x + (size_t)tile * (16 * IN_F) + (size_t)arow * IN_F + kgrp * 8;

    // depth-4 prefetch in NAMED registers
    f32x4 p0a = *(const f32x4*)(xr);           f32x4 p0b = *(const f32x4*)(xr + 4);
    f32x4 p1a = *(const f32x4*)(xr + 32);      f32x4 p1b = *(const f32x4*)(xr + 36);
    f32x4 p2a = *(const f32x4*)(xr + 64);      f32x4 p2b = *(const f32x4*)(xr + 68);
    f32x4 p3a = *(const f32x4*)(xr + 96);      f32x4 p3b = *(const f32x4*)(xr + 100);

    f32x4 acc0 = {0.f,0.f,0.f,0.f}, acc1 = {0.f,0.f,0.f,0.f};
    f32x4 acc2 = {0.f,0.f,0.f,0.f}, acc3 = {0.f,0.f,0.f,0.f};

    // one K-step: convert P -> a, prefetch step S+4 into P, 4 MFMAs (one per ct)
    #define STEP(P, S)                                                             \
    {                                                                              \
        bf16x8 a;                                                                  \
        a[0]=f2bf(P##a.x); a[1]=f2bf(P##a.y); a[2]=f2bf(P##a.z); a[3]=f2bf(P##a.w);\
        a[4]=f2bf(P##b.x); a[5]=f2bf(P##b.y); a[6]=f2bf(P##b.z); a[7]=f2bf(P##b.w);\
        const int sp = (S) + 4;                                                    \
        if (sp < NSTEP) {                                                          \
            const float* src = xr + sp * 32;                                       \
            if (sp == NSTEP - 1 && kgrp >= 2) src = xr;   /* clamp OOB tail */     \
            P##a = *(const f32x4*)src;                                             \
            P##b = *(const f32x4*)(src + 4);                                       \
        }                                                                          \
        acc0 = __builtin_amdgcn_mfma_f32_16x16x32_bf16(a, bfl[(0*NSTEP+(S))*64 + lane], acc0, 0, 0, 0); \
        acc1 = __builtin_amdgcn_mfma_f32_16x16x32_bf16(a, bfl[(1*NSTEP+(S))*64 + lane], acc1, 0, 0, 0); \
        acc2 = __builtin_amdgcn_mfma_f32_16x16x32_bf16(a, bfl[(2*NSTEP+(S))*64 + lane], acc2, 0, 0, 0); \
        acc3 = __builtin_amdgcn_mfma_f32_16x16x32_bf16(a, bfl[(3*NSTEP+(S))*64 + lane], acc3, 0, 0, 0); \
    }

    #pragma unroll
    for (int g = 0; g < 6; ++g) {        // steps 0..23
        const int s0 = g * 4;
        STEP(p0, s0 + 0)
        STEP(p1, s0 + 1)
        STEP(p2, s0 + 2)
        STEP(p3, s0 + 3)
    }
    {   // tail step 24 (k 768..799; real data ends at 783 -> zero kgrp>=2)
        bf16x8 a;
        a[0]=f2bf(p0a.x); a[1]=f2bf(p0a.y); a[2]=f2bf(p0a.z); a[3]=f2bf(p0a.w);
        a[4]=f2bf(p0b.x); a[5]=f2bf(p0b.y); a[6]=f2bf(p0b.z); a[7]=f2bf(p0b.w);
        if (kgrp >= 2) {
            #pragma unroll
            for (int j = 0; j < 8; ++j) a[j] = 0;
        }
        acc0 = __builtin_amdgcn_mfma_f32_16x16x32_bf16(a, bfl[(0*NSTEP+24)*64 + lane], acc0, 0, 0, 0);
        acc1 = __builtin_amdgcn_mfma_f32_16x16x32_bf16(a, bfl[(1*NSTEP+24)*64 + lane], acc1, 0, 0, 0);
        acc2 = __builtin_amdgcn_mfma_f32_16x16x32_bf16(a, bfl[(2*NSTEP+24)*64 + lane], acc2, 0, 0, 0);
        acc3 = __builtin_amdgcn_mfma_f32_16x16x32_bf16(a, bfl[(3*NSTEP+24)*64 + lane], acc3, 0, 0, 0);
    }
    #undef STEP

    // ---- per-wave out staging (same-wave ds ordering, no barrier) ----
    float* ob = ostage[wave];
    #define STORECT(ACC, CT)                                              \
    {                                                                     \
        const int col = (CT) * 16 + arow;     /* C col = lane&15 */       \
        if (col < OUT_F) {                                                \
            _Pragma("unroll")                                             \
            for (int j = 0; j < 4; ++j)       /* C row = (lane>>4)*4+j */ \
                ob[(kgrp * 4 + j) * OUT_F + col] = ACC[j];                \
        }                                                                 \
    }
    STORECT(acc0, 0) STORECT(acc1, 1) STORECT(acc2, 2) STORECT(acc3, 3)
    #undef STORECT

    float* og = out + (size_t)tile * (16 * OUT_F);
    #pragma unroll
    for (int r = 0; r < 4; ++r) {
        const int idx = lane + r * 64;
        if (idx < (16 * OUT_F) / 4)
            *((f32x4*)og + idx) = *((const f32x4*)ob + idx);
    }
}

extern "C" void kernel_launch(void* const* d_in, const int* in_sizes, int n_in,
                              void* d_out, int out_size, void* d_ws, size_t ws_size,
                              hipStream_t stream) {
    const float* x      = (const float*)d_in[0];
    const int*   wq     = (const int*)d_in[1];
    const float* scaler = (const float*)d_in[2];
    float*       out    = (float*)d_out;
    MNISTQuant_48687749267957_kernel<<<NBLK, NTHREADS, 0, stream>>>(x, wq, scaler, out);
}

// Round 5
// 43.491 us; speedup vs baseline: 3.3718x; 1.0797x over previous
//
#include <hip/hip_runtime.h>
#include <hip/hip_bf16.h>
#include <stdint.h>

// MNISTQuant: out[65536,50] = x[65536,784] @ (int8_w[784,50] * scaler)
// R5: R4 + (1) k-permuted fragment mapping so every global load is a
// contiguous 64 B per row (halves L1 transactions; clean K-tail),
// (2) x-prefetch issued before the B-table prologue, (3) wq staged
// coalesced through LDS (overlaid on out-staging). Wave-owns-tile,
// barrier-free steady state, all registers named (no rule-#20 scratch).

typedef __attribute__((ext_vector_type(8))) short bf16x8;
typedef __attribute__((ext_vector_type(4))) float f32x4;

#define IN_F 784
#define OUT_F 50
#define NSTEP 25              // K padded 784 -> 800 (25 x 32)
#define NCT 4                 // col tiles (50 -> 64)
#define NBLK 256              // 1 block/CU
#define NTHREADS 1024         // 16 waves, 1 tile per wave

__device__ __forceinline__ short f2bf(float f) {
    return (short)__builtin_bit_cast(unsigned short, __float2bfloat16(f));
}

__global__ __launch_bounds__(NTHREADS, 4) void MNISTQuant_48687749267957_kernel(
    const float* __restrict__ x,
    const int* __restrict__ wq,          // int8 weights delivered as int32
    const float* __restrict__ scaler,
    float* __restrict__ out)
{
    __shared__ bf16x8 bfl[NCT * NSTEP * 64];      // 102,400 B fragment table
    __shared__ float  ostage[16][16 * OUT_F];     //  51,200 B out staging
    // wq staging overlays ostage (39,200 B); dead after prologue barrier #2
    signed char* w8 = (signed char*)&ostage[0][0];

    const int tid  = threadIdx.x;
    const int lane = tid & 63;
    const int wave = tid >> 6;
    const int arow = lane & 15;          // A row (m) within tile
    const int kgrp = lane >> 4;
    const float scl = scaler[0];

    // k-permutation: hw slot (s, kgrp, j) holds logical
    //   kappa = s*32 + kgrp*4 + j            (j<4,  from pa: row bytes [s*128, s*128+64))
    //   kappa = s*32 + 16 + kgrp*4 + (j-4)   (j>=4, from pb: row bytes [s*128+64, s*128+128))
    // B-table built with the same kappa -> result invariant.

    const int tile = blockIdx.x * 16 + wave;
    const float* xr = x + (size_t)tile * (16 * IN_F) + (size_t)arow * IN_F + kgrp * 4;

    // ---- issue depth-6 x prefetch FIRST (named registers) ----
    f32x4 p0a = *(const f32x4*)(xr +   0), p0b = *(const f32x4*)(xr +  16);
    f32x4 p1a = *(const f32x4*)(xr +  32), p1b = *(const f32x4*)(xr +  48);
    f32x4 p2a = *(const f32x4*)(xr +  64), p2b = *(const f32x4*)(xr +  80);
    f32x4 p3a = *(const f32x4*)(xr +  96), p3b = *(const f32x4*)(xr + 112);
    f32x4 p4a = *(const f32x4*)(xr + 128), p4b = *(const f32x4*)(xr + 144);
    f32x4 p5a = *(const f32x4*)(xr + 160), p5b = *(const f32x4*)(xr + 176);

    // ---- Prologue A: stage wq into LDS, coalesced int4 ----
    for (int i = tid; i < (IN_F * OUT_F) / 4; i += NTHREADS) {   // 9800/4 = 2450
        const int4 v = ((const int4*)wq)[i];
        unsigned int packed = (v.x & 255) | ((v.y & 255) << 8) |
                              ((v.z & 255) << 16) | (((unsigned int)v.w) << 24);
        ((unsigned int*)w8)[i] = packed;
    }
    __syncthreads();

    // ---- Prologue B: fragment-order dequantized B table (kappa mapping) ----
    for (int g = tid; g < NCT * NSTEP * 64; g += NTHREADS) {
        const int l   = g & 63;
        const int cs  = g >> 6;
        const int ct  = cs / NSTEP;
        const int s   = cs - ct * NSTEP;
        const int col = ct * 16 + (l & 15);
        const int kg  = l >> 4;
        const int k0  = s * 32 + kg * 4;         // j<4: k0+j   (always < 784)
        const int k1  = k0 + 16;                 // j>=4: k1+(j-4) (OOB iff s==24)
        bf16x8 f;
        #pragma unroll
        for (int j = 0; j < 4; ++j) {
            float w = (col < OUT_F) ? (float)w8[(k0 + j) * OUT_F + col] * scl : 0.f;
            f[j] = f2bf(w);
        }
        #pragma unroll
        for (int j = 0; j < 4; ++j) {
            float w = (col < OUT_F && s < NSTEP - 1)
                        ? (float)w8[(k1 + j) * OUT_F + col] * scl : 0.f;
            f[4 + j] = f2bf(w);
        }
        bfl[g] = f;
    }
    __syncthreads();   // w8 dead; bfl read-only; ostage free for epilogue

    // two base pointers so all ds_read offsets fit 16-bit immediates
    const bf16x8* bw_lo = bfl + lane;                     // ct 0,1
    const bf16x8* bw_hi = bfl + 2 * NSTEP * 64 + lane;    // ct 2,3

    f32x4 acc0 = {0.f,0.f,0.f,0.f}, acc1 = {0.f,0.f,0.f,0.f};
    f32x4 acc2 = {0.f,0.f,0.f,0.f}, acc3 = {0.f,0.f,0.f,0.f};

    #define STEP(P, S)                                                             \
    {                                                                              \
        bf16x8 a;                                                                  \
        a[0]=f2bf(P##a.x); a[1]=f2bf(P##a.y); a[2]=f2bf(P##a.z); a[3]=f2bf(P##a.w);\
        a[4]=f2bf(P##b.x); a[5]=f2bf(P##b.y); a[6]=f2bf(P##b.z); a[7]=f2bf(P##b.w);\
        if ((S) + 6 < NSTEP - 1) {                                                 \
            P##a = *(const f32x4*)(xr + ((S) + 6) * 32);                           \
            P##b = *(const f32x4*)(xr + ((S) + 6) * 32 + 16);                      \
        } else if ((S) + 6 == NSTEP - 1) {                                         \
            P##a = *(const f32x4*)(xr + (NSTEP - 1) * 32);  /* k 768..783 only */  \
        }                                                                          \
        acc0 = __builtin_amdgcn_mfma_f32_16x16x32_bf16(a, bw_lo[(0*NSTEP+(S))*64], acc0, 0, 0, 0); \
        acc1 = __builtin_amdgcn_mfma_f32_16x16x32_bf16(a, bw_lo[(1*NSTEP+(S))*64], acc1, 0, 0, 0); \
        acc2 = __builtin_amdgcn_mfma_f32_16x16x32_bf16(a, bw_hi[(0*NSTEP+(S))*64], acc2, 0, 0, 0); \
        acc3 = __builtin_amdgcn_mfma_f32_16x16x32_bf16(a, bw_hi[(1*NSTEP+(S))*64], acc3, 0, 0, 0); \
    }

    #pragma unroll
    for (int g = 0; g < 4; ++g) {        // steps 0..23, depth-6 rotation
        const int s0 = g * 6;
        STEP(p0, s0 + 0)
        STEP(p1, s0 + 1)
        STEP(p2, s0 + 2)
        STEP(p3, s0 + 3)
        STEP(p4, s0 + 4)
        STEP(p5, s0 + 5)
    }
    {   // tail step 24: pa real (k 768..783), upper half zero
        bf16x8 a;
        a[0]=f2bf(p0a.x); a[1]=f2bf(p0a.y); a[2]=f2bf(p0a.z); a[3]=f2bf(p0a.w);
        a[4]=0; a[5]=0; a[6]=0; a[7]=0;
        acc0 = __builtin_amdgcn_mfma_f32_16x16x32_bf16(a, bw_lo[(0*NSTEP+24)*64], acc0, 0, 0, 0);
        acc1 = __builtin_amdgcn_mfma_f32_16x16x32_bf16(a, bw_lo[(1*NSTEP+24)*64], acc1, 0, 0, 0);
        acc2 = __builtin_amdgcn_mfma_f32_16x16x32_bf16(a, bw_hi[(0*NSTEP+24)*64], acc2, 0, 0, 0);
        acc3 = __builtin_amdgcn_mfma_f32_16x16x32_bf16(a, bw_hi[(1*NSTEP+24)*64], acc3, 0, 0, 0);
    }
    #undef STEP

    // ---- per-wave out staging (same-wave ds ordering, no barrier) ----
    float* ob = ostage[wave];
    #define STORECT(ACC, CT)                                              \
    {                                                                     \
        const int col = (CT) * 16 + arow;     /* C col = lane&15 */       \
        if (col < OUT_F) {                                                \
            _Pragma("unroll")                                             \
            for (int j = 0; j < 4; ++j)       /* C row = (lane>>4)*4+j */ \
                ob[(kgrp * 4 + j) * OUT_F + col] = ACC[j];                \
        }                                                                 \
    }
    STORECT(acc0, 0) STORECT(acc1, 1) STORECT(acc2, 2) STORECT(acc3, 3)
    #undef STORECT

    float* og = out + (size_t)tile * (16 * OUT_F);
    #pragma unroll
    for (int r = 0; r < 4; ++r) {
        const int idx = lane + r * 64;
        if (idx < (16 * OUT_F) / 4)
            *((f32x4*)og + idx) = *((const f32x4*)ob + idx);
    }
}

extern "C" void kernel_launch(void* const* d_in, const int* in_sizes, int n_in,
                              void* d_out, int out_size, void* d_ws, size_t ws_size,
                              hipStream_t stream) {
    const float* x      = (const float*)d_in[0];
    const int*   wq     = (const int*)d_in[1];
    const float* scaler = (const float*)d_in[2];
    float*       out    = (float*)d_out;
    MNISTQuant_48687749267957_kernel<<<NBLK, NTHREADS, 0, stream>>>(x, wq, scaler, out);
}